// Round 6
// baseline (790.996 us; speedup 1.0000x reference)
//
#include <hip/hip_runtime.h>

#define N_EDGES 3200000
#define N_NODES 100000
#define SFIX 16384.0f
#define INVSFIX 6.103515625e-05f

typedef unsigned short ushort_t;
typedef unsigned long long u64_t;
typedef __attribute__((ext_vector_type(8))) short bf16x8;  // 8 bf16 in 4 VGPRs
typedef __attribute__((ext_vector_type(4))) float f32x4;

// ---------- bf16 helpers ----------
__device__ inline unsigned short f2bf(float f) {
    unsigned u = __float_as_uint(f);
    u += 0x7fffu + ((u >> 16) & 1u);       // round-to-nearest-even
    return (unsigned short)(u >> 16);
}
__device__ inline unsigned pack_bf2(float lo, float hi) {
    return (unsigned)f2bf(lo) | ((unsigned)f2bf(hi) << 16);
}
__device__ inline bf16x8 u4_to_b8(uint4 u) {
    union { uint4 a; bf16x8 b; } c; c.a = u; return c.b;
}
// relu + fixed-point pack of two adjacent features into one u64
__device__ inline u64_t fixpair(float lo, float hi) {
    const unsigned ul = __float2uint_rn(fmaxf(lo, 0.0f) * SFIX);
    const unsigned uh = __float2uint_rn(fmaxf(hi, 0.0f) * SFIX);
    return (u64_t)ul | ((u64_t)uh << 32);
}

// ---------- pass 1: cast/transpose tables + acc64 zeroing (NO GEMMs) ----------
__global__ void __launch_bounds__(256) mpn_precompute(
    const float* __restrict__ x_node,
    const float* __restrict__ We1, const float* __restrict__ be1,
    const float* __restrict__ We2, const float* __restrict__ be2,
    const float* __restrict__ Wn1, const float* __restrict__ bn1,
    const float* __restrict__ Wn2,
    unsigned* __restrict__ xb,
    ushort_t* __restrict__ WaT, ushort_t* __restrict__ WbT,
    ushort_t* __restrict__ WcTp, ushort_t* __restrict__ W2T,
    ushort_t* __restrict__ NaT, ushort_t* __restrict__ NbTp,
    ushort_t* __restrict__ N2T, float* __restrict__ be2p,
    u64_t* __restrict__ acc64)           // zeroed here (fixed-point accumulator)
{
    const int n = blockIdx.x * 256 + threadIdx.x;

    if (n < 1024) {
        const int o = n >> 5, k = n & 31;
        WaT[n] = f2bf(We1[k * 32 + o]);
        WbT[n] = f2bf(We1[(32 + k) * 32 + o]);
        WcTp[n] = (k < 6) ? f2bf(We1[(64 + k) * 32 + o])
                          : ((k == 6) ? f2bf(be1[o]) : (ushort_t)0);
    }
    if (n < 512) {
        const int o = n >> 5, k = n & 31;
        W2T[n] = (o < 6) ? f2bf(We2[k * 6 + o]) : (ushort_t)0;
    }
    if (n < 2048) {
        const int o = n >> 5, k = n & 31;
        NaT[n] = f2bf(Wn1[k * 64 + o]);
        NbTp[n] = (k < 6) ? f2bf(Wn1[(32 + k) * 64 + o])
                          : ((k == 6) ? f2bf(bn1[o]) : (ushort_t)0);
        N2T[n] = f2bf(Wn2[(n & 63) * 32 + (n >> 6)]);   // [o=n>>6][k=n&63]
    }
    if (n < 16) be2p[n] = (n < 6) ? be2[n] : 0.0f;

    if (n >= N_NODES) return;

    // zero the fixed-point accumulator (128 B/node)
    {
        uint4 z = make_uint4(0, 0, 0, 0);
        uint4* a = (uint4*)(acc64 + (size_t)n * 16);
        #pragma unroll
        for (int i = 0; i < 8; ++i) a[i] = z;
    }
    // bf16 node-feature row
    {
        const float4* px = (const float4*)(x_node + (size_t)n * 32);
        unsigned* xr = xb + (size_t)n * 16;
        #pragma unroll
        for (int i = 0; i < 8; ++i) {
            float4 v = px[i];
            xr[2*i+0] = pack_bf2(v.x, v.y);
            xr[2*i+1] = pack_bf2(v.z, v.w);
        }
    }
}

// ---------- pass 2: all-MFMA transposed pipeline, 128 edges/block ----------
// Per wave: 32 edges as 2 n-tiles of 16; wave-private LDS staging (no barrier);
// 8 blocks/CU (launch_bounds(256,8)) for latency hiding.
__global__ void __launch_bounds__(256, 8) mpn_main(
    const ushort_t* __restrict__ xb,
    const ushort_t* __restrict__ WaT, const ushort_t* __restrict__ WbT,
    const ushort_t* __restrict__ WcTp, const ushort_t* __restrict__ W2T,
    const ushort_t* __restrict__ NaT, const ushort_t* __restrict__ NbTp,
    const ushort_t* __restrict__ N2T,
    const float* __restrict__ be2p, const float* __restrict__ bn2,
    const float* __restrict__ x_edge,
    const int* __restrict__ src, const int* __restrict__ dst,
    u64_t* __restrict__ acc64,    // [N_NODES, 16] packed fixed-point
    float* __restrict__ em_out)   // [N_EDGES, 6]
{
    __shared__ u64_t s_a64[4][32 * 17];    // per-wave staged rows, pad 17 (17408 B)
    __shared__ int   s_d[4][32];

    const int tid  = threadIdx.x;
    const int lane = tid & 63;
    const int wave = tid >> 6;
    const int q    = (lane >> 4) & 3;
    const int l15  = lane & 15;
    const int hi   = q >> 1;

    const int eb = blockIdx.x * 128 + wave * 32;

    // ---- hoisted gathers for both sub-tiles (all latency in flight together)
    int dv[2], sv[2];
    #pragma unroll
    for (int t = 0; t < 2; ++t) {
        const int e = eb + t * 16 + l15;
        dv[t] = dst[e];
        sv[t] = src[e];
    }
    bf16x8 xd[2], xs[2];
    #pragma unroll
    for (int t = 0; t < 2; ++t) {
        xd[t] = *(const bf16x8*)(xb + (size_t)dv[t] * 32 + q * 8);  // B[edge][k]
        xs[t] = *(const bf16x8*)(xb + (size_t)sv[t] * 32 + q * 8);
    }
    uint4 bxeU[2];
    #pragma unroll
    for (int t = 0; t < 2; ++t) {
        uint4 u = make_uint4(0, 0, 0, 0);
        if (q == 0) {   // only k=0..7 lanes carry xe (k6 = 1.0 -> be1 fold)
            const int e = eb + t * 16 + l15;
            const float2* pe = (const float2*)(x_edge + (size_t)e * 6);
            float2 a = pe[0], b = pe[1], c = pe[2];
            u = make_uint4(pack_bf2(a.x, a.y), pack_bf2(b.x, b.y),
                           pack_bf2(c.x, c.y), pack_bf2(1.0f, 0.0f));
        }
        bxeU[t] = u;
    }

    const int sAl = ((q & 1) << 5) + l15;   // src lane for k-low half
    const int sBl = sAl + 16;               // src lane for k-high half

    #pragma unroll
    for (int t = 0; t < 2; ++t) {
        // ---- h1^T = relu(WaT·xd + WbT·xs + WcTp·xe)   [32 x 16e]
        f32x4 h1c[2];
        #pragma unroll
        for (int m = 0; m < 2; ++m) {
            const int row = m * 16 + l15;
            f32x4 acc = (f32x4)0.f;
            acc = __builtin_amdgcn_mfma_f32_16x16x32_bf16(
                *(const bf16x8*)(WaT + row * 32 + q * 8), xd[t], acc, 0, 0, 0);
            acc = __builtin_amdgcn_mfma_f32_16x16x32_bf16(
                *(const bf16x8*)(WbT + row * 32 + q * 8), xs[t], acc, 0, 0, 0);
            acc = __builtin_amdgcn_mfma_f32_16x16x32_bf16(
                *(const bf16x8*)(WcTp + row * 32 + q * 8), u4_to_b8(bxeU[t]), acc, 0, 0, 0);
            #pragma unroll
            for (int r = 0; r < 4; ++r) acc[r] = fmaxf(acc[r], 0.f);
            h1c[m] = acc;
        }

        // ---- C->B: lane needs h1[edge=l15][k=q*8+j]
        unsigned u00 = pack_bf2(h1c[0][0], h1c[0][1]);
        unsigned u01 = pack_bf2(h1c[0][2], h1c[0][3]);
        unsigned u10 = pack_bf2(h1c[1][0], h1c[1][1]);
        unsigned u11 = pack_bf2(h1c[1][2], h1c[1][3]);
        unsigned a0 = __shfl((int)u00, sAl), a1 = __shfl((int)u01, sAl);
        unsigned a2 = __shfl((int)u10, sAl), a3 = __shfl((int)u11, sAl);
        unsigned b0 = __shfl((int)u00, sBl), b1 = __shfl((int)u01, sBl);
        unsigned b2 = __shfl((int)u10, sBl), b3 = __shfl((int)u11, sBl);
        uint4 bh1 = make_uint4(hi ? a2 : a0, hi ? a3 : a1,
                               hi ? b2 : b0, hi ? b3 : b1);

        // ---- em^T = W2T · h1^T   [16(6 valid) x 16e]
        f32x4 emc = __builtin_amdgcn_mfma_f32_16x16x32_bf16(
            *(const bf16x8*)(W2T + l15 * 32 + q * 8), u4_to_b8(bh1),
            (f32x4)0.f, 0, 0, 0);
        const float emv0 = fmaxf(emc[0] + be2p[q * 4 + 0], 0.f);
        const float emv1 = fmaxf(emc[1] + be2p[q * 4 + 1], 0.f);
        const float emv2 = fmaxf(emc[2] + be2p[q * 4 + 2], 0.f);
        const float emv3 = fmaxf(emc[3] + be2p[q * 4 + 3], 0.f);

        // em_out: q0 holds feats 0-3, q1 holds feats 4-5 (rows 4,5)
        const int e = eb + t * 16 + l15;
        if (q == 0) {
            *(float2*)(em_out + (size_t)e * 6 + 0) = make_float2(emv0, emv1);
            *(float2*)(em_out + (size_t)e * 6 + 2) = make_float2(emv2, emv3);
        } else if (q == 1) {
            *(float2*)(em_out + (size_t)e * 6 + 4) = make_float2(emv0, emv1);
        }

        // ---- C->B for h2: em[edge][k<6], k6 = 1.0 (bn1 fold)
        const float f4 = __shfl(emv0, l15 + 16);   // feat 4 from q=1
        const float f5 = __shfl(emv1, l15 + 16);   // feat 5 from q=1
        uint4 bem = make_uint4(0, 0, 0, 0);
        if (q == 0)
            bem = make_uint4(pack_bf2(emv0, emv1), pack_bf2(emv2, emv3),
                             pack_bf2(f4, f5), pack_bf2(1.0f, 0.0f));

        // ---- h2^T = relu(NbTp·em + NaT·xd)   [64 x 16e]
        f32x4 h2c[4];
        #pragma unroll
        for (int m = 0; m < 4; ++m) {
            const int row = m * 16 + l15;
            f32x4 acc = __builtin_amdgcn_mfma_f32_16x16x32_bf16(
                *(const bf16x8*)(NbTp + row * 32 + q * 8), u4_to_b8(bem),
                (f32x4)0.f, 0, 0, 0);
            acc = __builtin_amdgcn_mfma_f32_16x16x32_bf16(
                *(const bf16x8*)(NaT + row * 32 + q * 8), xd[t], acc, 0, 0, 0);
            #pragma unroll
            for (int r = 0; r < 4; ++r) acc[r] = fmaxf(acc[r], 0.f);
            h2c[m] = acc;
        }

        // ---- C->B for nm: lane needs h2[edge][k = kt*32 + q*8 + j]
        unsigned v00 = pack_bf2(h2c[0][0], h2c[0][1]), v01 = pack_bf2(h2c[0][2], h2c[0][3]);
        unsigned v10 = pack_bf2(h2c[1][0], h2c[1][1]), v11 = pack_bf2(h2c[1][2], h2c[1][3]);
        unsigned v20 = pack_bf2(h2c[2][0], h2c[2][1]), v21 = pack_bf2(h2c[2][2], h2c[2][3]);
        unsigned v30 = pack_bf2(h2c[3][0], h2c[3][1]), v31 = pack_bf2(h2c[3][2], h2c[3][3]);
        unsigned c0 = __shfl((int)v00, sAl), c1 = __shfl((int)v01, sAl);
        unsigned c2 = __shfl((int)v10, sAl), c3 = __shfl((int)v11, sAl);
        unsigned d0 = __shfl((int)v00, sBl), d1 = __shfl((int)v01, sBl);
        unsigned d2 = __shfl((int)v10, sBl), d3 = __shfl((int)v11, sBl);
        uint4 bh2k0 = make_uint4(hi ? c2 : c0, hi ? c3 : c1,
                                 hi ? d2 : d0, hi ? d3 : d1);
        unsigned g0 = __shfl((int)v20, sAl), g1 = __shfl((int)v21, sAl);
        unsigned g2 = __shfl((int)v30, sAl), g3 = __shfl((int)v31, sAl);
        unsigned k0 = __shfl((int)v20, sBl), k1 = __shfl((int)v21, sBl);
        unsigned k2 = __shfl((int)v30, sBl), k3 = __shfl((int)v31, sBl);
        uint4 bh2k1 = make_uint4(hi ? g2 : g0, hi ? g3 : g1,
                                 hi ? k2 : k0, hi ? k3 : k1);

        // ---- nm^T = N2T · h2^T   [32 x 16e]
        f32x4 nm0 = __builtin_amdgcn_mfma_f32_16x16x32_bf16(
            *(const bf16x8*)(N2T + (0 * 16 + l15) * 64 + q * 8), u4_to_b8(bh2k0),
            (f32x4)0.f, 0, 0, 0);
        nm0 = __builtin_amdgcn_mfma_f32_16x16x32_bf16(
            *(const bf16x8*)(N2T + (0 * 16 + l15) * 64 + 32 + q * 8), u4_to_b8(bh2k1),
            nm0, 0, 0, 0);
        f32x4 nm1 = __builtin_amdgcn_mfma_f32_16x16x32_bf16(
            *(const bf16x8*)(N2T + (1 * 16 + l15) * 64 + q * 8), u4_to_b8(bh2k0),
            (f32x4)0.f, 0, 0, 0);
        nm1 = __builtin_amdgcn_mfma_f32_16x16x32_bf16(
            *(const bf16x8*)(N2T + (1 * 16 + l15) * 64 + 32 + q * 8), u4_to_b8(bh2k1),
            nm1, 0, 0, 0);

        // ---- stage relu(nm + bn2) as packed fixed-point u64 (feats 2j, 2j+1)
        // row-stride 17 u64 breaks the 16-way bank conflict of stride 16.
        {
            const int row = t * 16 + l15;
            u64_t* sr = &s_a64[wave][row * 17];
            const int f = q * 4;
            sr[q*2 + 0]     = fixpair(nm0[0] + bn2[f+0], nm0[1] + bn2[f+1]);
            sr[q*2 + 1]     = fixpair(nm0[2] + bn2[f+2], nm0[3] + bn2[f+3]);
            sr[8 + q*2 + 0] = fixpair(nm1[0] + bn2[16+f+0], nm1[1] + bn2[16+f+1]);
            sr[8 + q*2 + 1] = fixpair(nm1[2] + bn2[16+f+2], nm1[3] + bn2[16+f+3]);
        }
        if (q == 0) s_d[wave][t * 16 + l15] = dv[t];
    }
    // NO __syncthreads: staging and drain are wave-private (wave-synchronous LDS).

    // ---- coalesced u64 atomic drain: this wave's 32 rows x 16 u64, 1 op each
    {
        const u64_t* sw = s_a64[wave];
        const int*   dw = s_d[wave];
        #pragma unroll
        for (int it = 0; it < 8; ++it) {
            const int idx = it * 64 + lane;
            const int row = idx >> 4;
            const int j   = idx & 15;
            atomicAdd(acc64 + (size_t)dw[row] * 16 + j, sw[row * 17 + j]);
        }
    }
}

// ---------- pass 3: fixed-point -> f32 output ----------
__global__ void __launch_bounds__(256) mpn_convert(
    const u64_t* __restrict__ acc64,
    float* __restrict__ nm_out)
{
    const int n = blockIdx.x * 256 + threadIdx.x;
    if (n >= N_NODES) return;
    const u64_t* a = acc64 + (size_t)n * 16;
    float4* o = (float4*)(nm_out + (size_t)n * 32);
    #pragma unroll
    for (int i = 0; i < 8; ++i) {
        const u64_t v0 = a[2*i], v1 = a[2*i+1];
        o[i] = make_float4((float)(unsigned)v0         * INVSFIX,
                           (float)(unsigned)(v0 >> 32) * INVSFIX,
                           (float)(unsigned)v1         * INVSFIX,
                           (float)(unsigned)(v1 >> 32) * INVSFIX);
    }
}

extern "C" void kernel_launch(void* const* d_in, const int* in_sizes, int n_in,
                              void* d_out, int out_size, void* d_ws, size_t ws_size,
                              hipStream_t stream) {
    const float* x_node = (const float*)d_in[0];
    const float* x_edge = (const float*)d_in[1];
    const int*   src    = (const int*)d_in[2];
    const int*   dst    = (const int*)d_in[3];
    const float* We1 = (const float*)d_in[4];
    const float* be1 = (const float*)d_in[5];
    const float* We2 = (const float*)d_in[6];
    const float* be2 = (const float*)d_in[7];
    const float* Wn1 = (const float*)d_in[8];
    const float* bn1 = (const float*)d_in[9];
    const float* Wn2 = (const float*)d_in[10];
    const float* bn2 = (const float*)d_in[11];

    float* nm_out = (float*)d_out;                        // [N_NODES*32]
    float* em_out = (float*)d_out + (size_t)N_NODES * 32; // [N_EDGES*6]

    // workspace layout (bytes):
    //   xb    @ 0        : 100000*64 = 6,400,000
    //   WaT   @ 6400000  : 2048
    //   WbT   @ 6402048  : 2048
    //   WcTp  @ 6404096  : 2048
    //   W2T   @ 6406144  : 1024
    //   NaT   @ 6407168  : 4096
    //   NbTp  @ 6411264  : 4096
    //   N2T   @ 6415360  : 4096
    //   be2p  @ 6419456  : 64
    //   acc64 @ 6420480  : 100000*16*8 = 12,800,000   (8B aligned)
    char* ws = (char*)d_ws;
    unsigned* xb    = (unsigned*)ws;
    ushort_t* WaT   = (ushort_t*)(ws + 6400000);
    ushort_t* WbT   = (ushort_t*)(ws + 6402048);
    ushort_t* WcTp  = (ushort_t*)(ws + 6404096);
    ushort_t* W2T   = (ushort_t*)(ws + 6406144);
    ushort_t* NaT   = (ushort_t*)(ws + 6407168);
    ushort_t* NbTp  = (ushort_t*)(ws + 6411264);
    ushort_t* N2T   = (ushort_t*)(ws + 6415360);
    float*    be2p  = (float*)(ws + 6419456);
    u64_t*    acc64 = (u64_t*)(ws + 6420480);

    mpn_precompute<<<(N_NODES + 255) / 256, 256, 0, stream>>>(
        x_node, We1, be1, We2, be2, Wn1, bn1, Wn2,
        xb, WaT, WbT, WcTp, W2T, NaT, NbTp, N2T, be2p, acc64);

    mpn_main<<<N_EDGES / 128, 256, 0, stream>>>(
        (const ushort_t*)xb, WaT, WbT, WcTp, W2T, NaT, NbTp, N2T,
        be2p, bn2, x_edge, src, dst, acc64, em_out);

    mpn_convert<<<(N_NODES + 255) / 256, 256, 0, stream>>>(acc64, nm_out);
}

// Round 7
// 686.059 us; speedup vs baseline: 1.1530x; 1.1530x over previous
//
#include <hip/hip_runtime.h>

#define N_EDGES 3200000
#define N_NODES 100000
#define SFIX 16384.0f
#define INVSFIX 6.103515625e-05f

typedef unsigned short ushort_t;
typedef unsigned long long u64_t;
typedef __attribute__((ext_vector_type(8))) short bf16x8;  // 8 bf16 in 4 VGPRs
typedef __attribute__((ext_vector_type(4))) float f32x4;

// ---------- bf16 helpers ----------
__device__ inline unsigned short f2bf(float f) {
    unsigned u = __float_as_uint(f);
    u += 0x7fffu + ((u >> 16) & 1u);       // round-to-nearest-even
    return (unsigned short)(u >> 16);
}
__device__ inline unsigned pack_bf2(float lo, float hi) {
    return (unsigned)f2bf(lo) | ((unsigned)f2bf(hi) << 16);
}
__device__ inline bf16x8 u4_to_b8(uint4 u) {
    union { uint4 a; bf16x8 b; } c; c.a = u; return c.b;
}
// relu + fixed-point pack of two adjacent features into one u64
__device__ inline u64_t fixpair(float lo, float hi) {
    const unsigned ul = __float2uint_rn(fmaxf(lo, 0.0f) * SFIX);
    const unsigned uh = __float2uint_rn(fmaxf(hi, 0.0f) * SFIX);
    return (u64_t)ul | ((u64_t)uh << 32);
}

// ---------- pass 1: cast/transpose tables + acc64 zeroing (NO GEMMs) ----------
__global__ void __launch_bounds__(256) mpn_precompute(
    const float* __restrict__ x_node,
    const float* __restrict__ We1, const float* __restrict__ be1,
    const float* __restrict__ We2, const float* __restrict__ be2,
    const float* __restrict__ Wn1, const float* __restrict__ bn1,
    const float* __restrict__ Wn2,
    unsigned* __restrict__ xb,
    ushort_t* __restrict__ WaT, ushort_t* __restrict__ WbT,
    ushort_t* __restrict__ WcTp, ushort_t* __restrict__ W2T,
    ushort_t* __restrict__ NaT, ushort_t* __restrict__ NbTp,
    ushort_t* __restrict__ N2T, float* __restrict__ be2p,
    u64_t* __restrict__ acc64)           // zeroed here (fixed-point accumulator)
{
    const int n = blockIdx.x * 256 + threadIdx.x;

    if (n < 1024) {
        const int o = n >> 5, k = n & 31;
        WaT[n] = f2bf(We1[k * 32 + o]);
        WbT[n] = f2bf(We1[(32 + k) * 32 + o]);
        WcTp[n] = (k < 6) ? f2bf(We1[(64 + k) * 32 + o])
                          : ((k == 6) ? f2bf(be1[o]) : (ushort_t)0);
    }
    if (n < 512) {
        const int o = n >> 5, k = n & 31;
        W2T[n] = (o < 6) ? f2bf(We2[k * 6 + o]) : (ushort_t)0;
    }
    if (n < 2048) {
        const int o = n >> 5, k = n & 31;
        NaT[n] = f2bf(Wn1[k * 64 + o]);
        NbTp[n] = (k < 6) ? f2bf(Wn1[(32 + k) * 64 + o])
                          : ((k == 6) ? f2bf(bn1[o]) : (ushort_t)0);
        N2T[n] = f2bf(Wn2[(n & 63) * 32 + (n >> 6)]);   // [o=n>>6][k=n&63]
    }
    if (n < 16) be2p[n] = (n < 6) ? be2[n] : 0.0f;

    if (n >= N_NODES) return;

    // zero the fixed-point accumulator (128 B/node)
    {
        uint4 z = make_uint4(0, 0, 0, 0);
        uint4* a = (uint4*)(acc64 + (size_t)n * 16);
        #pragma unroll
        for (int i = 0; i < 8; ++i) a[i] = z;
    }
    // bf16 node-feature row
    {
        const float4* px = (const float4*)(x_node + (size_t)n * 32);
        unsigned* xr = xb + (size_t)n * 16;
        #pragma unroll
        for (int i = 0; i < 8; ++i) {
            float4 v = px[i];
            xr[2*i+0] = pack_bf2(v.x, v.y);
            xr[2*i+1] = pack_bf2(v.z, v.w);
        }
    }
}

// ---------- pass 2: all-MFMA transposed pipeline, 128 edges/block ----------
// Per wave: 32 edges as 2 n-tiles of 16; wave-private LDS staging (no barrier).
// launch_bounds(256,6): 6 blocks/CU (75% occ cap) with VGPR budget 85 —
// enough for the kernel's natural ~52 VGPR (R6's (256,8) forced 32+spills).
__global__ void __launch_bounds__(256, 6) mpn_main(
    const ushort_t* __restrict__ xb,
    const ushort_t* __restrict__ WaT, const ushort_t* __restrict__ WbT,
    const ushort_t* __restrict__ WcTp, const ushort_t* __restrict__ W2T,
    const ushort_t* __restrict__ NaT, const ushort_t* __restrict__ NbTp,
    const ushort_t* __restrict__ N2T,
    const float* __restrict__ be2p, const float* __restrict__ bn2,
    const float* __restrict__ x_edge,
    const int* __restrict__ src, const int* __restrict__ dst,
    u64_t* __restrict__ acc64,    // [N_NODES, 16] packed fixed-point
    float* __restrict__ em_out)   // [N_EDGES, 6]
{
    __shared__ u64_t s_a64[4][32 * 17];    // per-wave staged rows, pad 17 (17408 B)
    __shared__ int   s_d[4][32];

    const int tid  = threadIdx.x;
    const int lane = tid & 63;
    const int wave = tid >> 6;
    const int q    = (lane >> 4) & 3;
    const int l15  = lane & 15;
    const int hi   = q >> 1;

    const int eb = blockIdx.x * 128 + wave * 32;

    // ---- hoisted gathers for both sub-tiles (all latency in flight together)
    int dv[2], sv[2];
    #pragma unroll
    for (int t = 0; t < 2; ++t) {
        const int e = eb + t * 16 + l15;
        dv[t] = dst[e];
        sv[t] = src[e];
    }
    bf16x8 xd[2], xs[2];
    #pragma unroll
    for (int t = 0; t < 2; ++t) {
        xd[t] = *(const bf16x8*)(xb + (size_t)dv[t] * 32 + q * 8);  // B[edge][k]
        xs[t] = *(const bf16x8*)(xb + (size_t)sv[t] * 32 + q * 8);
    }
    uint4 bxeU[2];
    #pragma unroll
    for (int t = 0; t < 2; ++t) {
        uint4 u = make_uint4(0, 0, 0, 0);
        if (q == 0) {   // only k=0..7 lanes carry xe (k6 = 1.0 -> be1 fold)
            const int e = eb + t * 16 + l15;
            const float2* pe = (const float2*)(x_edge + (size_t)e * 6);
            float2 a = pe[0], b = pe[1], c = pe[2];
            u = make_uint4(pack_bf2(a.x, a.y), pack_bf2(b.x, b.y),
                           pack_bf2(c.x, c.y), pack_bf2(1.0f, 0.0f));
        }
        bxeU[t] = u;
    }

    const int sAl = ((q & 1) << 5) + l15;   // src lane for k-low half
    const int sBl = sAl + 16;               // src lane for k-high half

    #pragma unroll
    for (int t = 0; t < 2; ++t) {
        // ---- h1^T = relu(WaT·xd + WbT·xs + WcTp·xe)   [32 x 16e]
        f32x4 h1c[2];
        #pragma unroll
        for (int m = 0; m < 2; ++m) {
            const int row = m * 16 + l15;
            f32x4 acc = (f32x4)0.f;
            acc = __builtin_amdgcn_mfma_f32_16x16x32_bf16(
                *(const bf16x8*)(WaT + row * 32 + q * 8), xd[t], acc, 0, 0, 0);
            acc = __builtin_amdgcn_mfma_f32_16x16x32_bf16(
                *(const bf16x8*)(WbT + row * 32 + q * 8), xs[t], acc, 0, 0, 0);
            acc = __builtin_amdgcn_mfma_f32_16x16x32_bf16(
                *(const bf16x8*)(WcTp + row * 32 + q * 8), u4_to_b8(bxeU[t]), acc, 0, 0, 0);
            #pragma unroll
            for (int r = 0; r < 4; ++r) acc[r] = fmaxf(acc[r], 0.f);
            h1c[m] = acc;
        }

        // ---- C->B: lane needs h1[edge=l15][k=q*8+j]
        unsigned u00 = pack_bf2(h1c[0][0], h1c[0][1]);
        unsigned u01 = pack_bf2(h1c[0][2], h1c[0][3]);
        unsigned u10 = pack_bf2(h1c[1][0], h1c[1][1]);
        unsigned u11 = pack_bf2(h1c[1][2], h1c[1][3]);
        unsigned a0 = __shfl((int)u00, sAl), a1 = __shfl((int)u01, sAl);
        unsigned a2 = __shfl((int)u10, sAl), a3 = __shfl((int)u11, sAl);
        unsigned b0 = __shfl((int)u00, sBl), b1 = __shfl((int)u01, sBl);
        unsigned b2 = __shfl((int)u10, sBl), b3 = __shfl((int)u11, sBl);
        uint4 bh1 = make_uint4(hi ? a2 : a0, hi ? a3 : a1,
                               hi ? b2 : b0, hi ? b3 : b1);

        // ---- em^T = W2T · h1^T   [16(6 valid) x 16e]
        f32x4 emc = __builtin_amdgcn_mfma_f32_16x16x32_bf16(
            *(const bf16x8*)(W2T + l15 * 32 + q * 8), u4_to_b8(bh1),
            (f32x4)0.f, 0, 0, 0);
        const float emv0 = fmaxf(emc[0] + be2p[q * 4 + 0], 0.f);
        const float emv1 = fmaxf(emc[1] + be2p[q * 4 + 1], 0.f);
        const float emv2 = fmaxf(emc[2] + be2p[q * 4 + 2], 0.f);
        const float emv3 = fmaxf(emc[3] + be2p[q * 4 + 3], 0.f);

        // em_out: q0 holds feats 0-3, q1 holds feats 4-5 (rows 4,5)
        const int e = eb + t * 16 + l15;
        if (q == 0) {
            *(float2*)(em_out + (size_t)e * 6 + 0) = make_float2(emv0, emv1);
            *(float2*)(em_out + (size_t)e * 6 + 2) = make_float2(emv2, emv3);
        } else if (q == 1) {
            *(float2*)(em_out + (size_t)e * 6 + 4) = make_float2(emv0, emv1);
        }

        // ---- C->B for h2: em[edge][k<6], k6 = 1.0 (bn1 fold)
        const float f4 = __shfl(emv0, l15 + 16);   // feat 4 from q=1
        const float f5 = __shfl(emv1, l15 + 16);   // feat 5 from q=1
        uint4 bem = make_uint4(0, 0, 0, 0);
        if (q == 0)
            bem = make_uint4(pack_bf2(emv0, emv1), pack_bf2(emv2, emv3),
                             pack_bf2(f4, f5), pack_bf2(1.0f, 0.0f));

        // ---- h2^T = relu(NbTp·em + NaT·xd)   [64 x 16e]
        f32x4 h2c[4];
        #pragma unroll
        for (int m = 0; m < 4; ++m) {
            const int row = m * 16 + l15;
            f32x4 acc = __builtin_amdgcn_mfma_f32_16x16x32_bf16(
                *(const bf16x8*)(NbTp + row * 32 + q * 8), u4_to_b8(bem),
                (f32x4)0.f, 0, 0, 0);
            acc = __builtin_amdgcn_mfma_f32_16x16x32_bf16(
                *(const bf16x8*)(NaT + row * 32 + q * 8), xd[t], acc, 0, 0, 0);
            #pragma unroll
            for (int r = 0; r < 4; ++r) acc[r] = fmaxf(acc[r], 0.f);
            h2c[m] = acc;
        }

        // ---- C->B for nm: lane needs h2[edge][k = kt*32 + q*8 + j]
        unsigned v00 = pack_bf2(h2c[0][0], h2c[0][1]), v01 = pack_bf2(h2c[0][2], h2c[0][3]);
        unsigned v10 = pack_bf2(h2c[1][0], h2c[1][1]), v11 = pack_bf2(h2c[1][2], h2c[1][3]);
        unsigned v20 = pack_bf2(h2c[2][0], h2c[2][1]), v21 = pack_bf2(h2c[2][2], h2c[2][3]);
        unsigned v30 = pack_bf2(h2c[3][0], h2c[3][1]), v31 = pack_bf2(h2c[3][2], h2c[3][3]);
        unsigned c0 = __shfl((int)v00, sAl), c1 = __shfl((int)v01, sAl);
        unsigned c2 = __shfl((int)v10, sAl), c3 = __shfl((int)v11, sAl);
        unsigned d0 = __shfl((int)v00, sBl), d1 = __shfl((int)v01, sBl);
        unsigned d2 = __shfl((int)v10, sBl), d3 = __shfl((int)v11, sBl);
        uint4 bh2k0 = make_uint4(hi ? c2 : c0, hi ? c3 : c1,
                                 hi ? d2 : d0, hi ? d3 : d1);
        unsigned g0 = __shfl((int)v20, sAl), g1 = __shfl((int)v21, sAl);
        unsigned g2 = __shfl((int)v30, sAl), g3 = __shfl((int)v31, sAl);
        unsigned k0 = __shfl((int)v20, sBl), k1 = __shfl((int)v21, sBl);
        unsigned k2 = __shfl((int)v30, sBl), k3 = __shfl((int)v31, sBl);
        uint4 bh2k1 = make_uint4(hi ? g2 : g0, hi ? g3 : g1,
                                 hi ? k2 : k0, hi ? k3 : k1);

        // ---- nm^T = N2T · h2^T   [32 x 16e]
        f32x4 nm0 = __builtin_amdgcn_mfma_f32_16x16x32_bf16(
            *(const bf16x8*)(N2T + (0 * 16 + l15) * 64 + q * 8), u4_to_b8(bh2k0),
            (f32x4)0.f, 0, 0, 0);
        nm0 = __builtin_amdgcn_mfma_f32_16x16x32_bf16(
            *(const bf16x8*)(N2T + (0 * 16 + l15) * 64 + 32 + q * 8), u4_to_b8(bh2k1),
            nm0, 0, 0, 0);
        f32x4 nm1 = __builtin_amdgcn_mfma_f32_16x16x32_bf16(
            *(const bf16x8*)(N2T + (1 * 16 + l15) * 64 + q * 8), u4_to_b8(bh2k0),
            (f32x4)0.f, 0, 0, 0);
        nm1 = __builtin_amdgcn_mfma_f32_16x16x32_bf16(
            *(const bf16x8*)(N2T + (1 * 16 + l15) * 64 + 32 + q * 8), u4_to_b8(bh2k1),
            nm1, 0, 0, 0);

        // ---- stage relu(nm + bn2) as packed fixed-point u64 (feats 2j, 2j+1)
        // row-stride 17 u64 breaks the 16-way bank conflict of stride 16.
        {
            const int row = t * 16 + l15;
            u64_t* sr = &s_a64[wave][row * 17];
            const int f = q * 4;
            sr[q*2 + 0]     = fixpair(nm0[0] + bn2[f+0], nm0[1] + bn2[f+1]);
            sr[q*2 + 1]     = fixpair(nm0[2] + bn2[f+2], nm0[3] + bn2[f+3]);
            sr[8 + q*2 + 0] = fixpair(nm1[0] + bn2[16+f+0], nm1[1] + bn2[16+f+1]);
            sr[8 + q*2 + 1] = fixpair(nm1[2] + bn2[16+f+2], nm1[3] + bn2[16+f+3]);
        }
        if (q == 0) s_d[wave][t * 16 + l15] = dv[t];
    }
    // NO __syncthreads: staging and drain are wave-private (wave-synchronous LDS).

    // ---- coalesced u64 atomic drain: this wave's 32 rows x 16 u64, 1 op each
    {
        const u64_t* sw = s_a64[wave];
        const int*   dw = s_d[wave];
        #pragma unroll
        for (int it = 0; it < 8; ++it) {
            const int idx = it * 64 + lane;
            const int row = idx >> 4;
            const int j   = idx & 15;
            atomicAdd(acc64 + (size_t)dw[row] * 16 + j, sw[row * 17 + j]);
        }
    }
}

// ---------- pass 3: fixed-point -> f32 output ----------
__global__ void __launch_bounds__(256) mpn_convert(
    const u64_t* __restrict__ acc64,
    float* __restrict__ nm_out)
{
    const int n = blockIdx.x * 256 + threadIdx.x;
    if (n >= N_NODES) return;
    const u64_t* a = acc64 + (size_t)n * 16;
    float4* o = (float4*)(nm_out + (size_t)n * 32);
    #pragma unroll
    for (int i = 0; i < 8; ++i) {
        const u64_t v0 = a[2*i], v1 = a[2*i+1];
        o[i] = make_float4((float)(unsigned)v0         * INVSFIX,
                           (float)(unsigned)(v0 >> 32) * INVSFIX,
                           (float)(unsigned)v1         * INVSFIX,
                           (float)(unsigned)(v1 >> 32) * INVSFIX);
    }
}

extern "C" void kernel_launch(void* const* d_in, const int* in_sizes, int n_in,
                              void* d_out, int out_size, void* d_ws, size_t ws_size,
                              hipStream_t stream) {
    const float* x_node = (const float*)d_in[0];
    const float* x_edge = (const float*)d_in[1];
    const int*   src    = (const int*)d_in[2];
    const int*   dst    = (const int*)d_in[3];
    const float* We1 = (const float*)d_in[4];
    const float* be1 = (const float*)d_in[5];
    const float* We2 = (const float*)d_in[6];
    const float* be2 = (const float*)d_in[7];
    const float* Wn1 = (const float*)d_in[8];
    const float* bn1 = (const float*)d_in[9];
    const float* Wn2 = (const float*)d_in[10];
    const float* bn2 = (const float*)d_in[11];

    float* nm_out = (float*)d_out;                        // [N_NODES*32]
    float* em_out = (float*)d_out + (size_t)N_NODES * 32; // [N_EDGES*6]

    // workspace layout (bytes):
    //   xb    @ 0        : 100000*64 = 6,400,000
    //   WaT   @ 6400000  : 2048
    //   WbT   @ 6402048  : 2048
    //   WcTp  @ 6404096  : 2048
    //   W2T   @ 6406144  : 1024
    //   NaT   @ 6407168  : 4096
    //   NbTp  @ 6411264  : 4096
    //   N2T   @ 6415360  : 4096
    //   be2p  @ 6419456  : 64
    //   acc64 @ 6420480  : 100000*16*8 = 12,800,000   (8B aligned)
    char* ws = (char*)d_ws;
    unsigned* xb    = (unsigned*)ws;
    ushort_t* WaT   = (ushort_t*)(ws + 6400000);
    ushort_t* WbT   = (ushort_t*)(ws + 6402048);
    ushort_t* WcTp  = (ushort_t*)(ws + 6404096);
    ushort_t* W2T   = (ushort_t*)(ws + 6406144);
    ushort_t* NaT   = (ushort_t*)(ws + 6407168);
    ushort_t* NbTp  = (ushort_t*)(ws + 6411264);
    ushort_t* N2T   = (ushort_t*)(ws + 6415360);
    float*    be2p  = (float*)(ws + 6419456);
    u64_t*    acc64 = (u64_t*)(ws + 6420480);

    mpn_precompute<<<(N_NODES + 255) / 256, 256, 0, stream>>>(
        x_node, We1, be1, We2, be2, Wn1, bn1, Wn2,
        xb, WaT, WbT, WcTp, W2T, NaT, NbTp, N2T, be2p, acc64);

    mpn_main<<<N_EDGES / 128, 256, 0, stream>>>(
        (const ushort_t*)xb, WaT, WbT, WcTp, W2T, NaT, NbTp, N2T,
        be2p, bn2, x_edge, src, dst, acc64, em_out);

    mpn_convert<<<(N_NODES + 255) / 256, 256, 0, stream>>>(acc64, nm_out);
}

// Round 8
// 550.436 us; speedup vs baseline: 1.4370x; 1.2464x over previous
//
#include <hip/hip_runtime.h>

#define N_EDGES 3200000
#define N_NODES 100000

typedef __attribute__((ext_vector_type(8))) short bf16x8;  // 8 bf16 in 4 VGPRs
typedef __attribute__((ext_vector_type(4))) float f32x4;

// ---------- bf16 helpers ----------
__device__ inline unsigned short f2bf(float f) {
    unsigned u = __float_as_uint(f);
    u += 0x7fffu + ((u >> 16) & 1u);       // round-to-nearest-even
    return (unsigned short)(u >> 16);
}
__device__ inline unsigned pack_bf2(float lo, float hi) {
    return (unsigned)f2bf(lo) | ((unsigned)f2bf(hi) << 16);
}
__device__ inline float bflo(unsigned u) { return __uint_as_float(u << 16); }
__device__ inline float bfhi(unsigned u) { return __uint_as_float(u & 0xffff0000u); }

// ---------- pass 1: per-node projections + output zeroing + Wn2^T ----------
// Pd[n] = [ x@We1[0:32] + be1  (32) | x@Wn1[0:32] + bn1  (64) ]  -> 48 packed uints
// Ps[n] = [ x@We1[32:64]       (32) ]                            -> 16 packed uints
__global__ void __launch_bounds__(256) mpn_precompute(
    const float* __restrict__ x_node,
    const float* __restrict__ We1, const float* __restrict__ be1,
    const float* __restrict__ Wn1, const float* __restrict__ bn1,
    const float* __restrict__ Wn2,
    unsigned* __restrict__ Pd, unsigned* __restrict__ Ps,
    short* __restrict__ Wn2T,            // [32][64] bf16
    float* __restrict__ nm_out)          // zeroed here (poisoned by harness)
{
    const int n = blockIdx.x * 256 + threadIdx.x;
    if (n >= N_NODES) return;

    // zero the atomic-accumulated output region
    {
        float4 z = make_float4(0.f, 0.f, 0.f, 0.f);
        float4* o = (float4*)(nm_out + (size_t)n * 32);
        #pragma unroll
        for (int i = 0; i < 8; ++i) o[i] = z;
    }
    // transpose Wn2 [64][32] -> Wn2T [32][64] bf16 (first 2048 threads)
    if (n < 2048) Wn2T[n] = (short)f2bf(Wn2[(n & 63) * 32 + (n >> 6)]);

    float x[32];
    {
        const float4* px = (const float4*)(x_node + (size_t)n * 32);
        #pragma unroll
        for (int i = 0; i < 8; ++i) {
            float4 v = px[i];
            x[4*i+0] = v.x; x[4*i+1] = v.y; x[4*i+2] = v.z; x[4*i+3] = v.w;
        }
    }

    float p1[32];
    #pragma unroll
    for (int j = 0; j < 32; ++j) p1[j] = be1[j];
    for (int k = 0; k < 32; ++k) {
        const float a = x[k];
        const float* w = We1 + k * 32;
        #pragma unroll
        for (int j = 0; j < 32; ++j) p1[j] = fmaf(a, w[j], p1[j]);
    }
    unsigned* pd = Pd + (size_t)n * 48;
    #pragma unroll
    for (int i = 0; i < 16; ++i) pd[i] = pack_bf2(p1[2*i], p1[2*i+1]);

    float p3[64];
    #pragma unroll
    for (int j = 0; j < 64; ++j) p3[j] = bn1[j];
    for (int k = 0; k < 32; ++k) {
        const float a = x[k];
        const float* w = Wn1 + k * 64;
        #pragma unroll
        for (int j = 0; j < 64; ++j) p3[j] = fmaf(a, w[j], p3[j]);
    }
    #pragma unroll
    for (int i = 0; i < 32; ++i) pd[16 + i] = pack_bf2(p3[2*i], p3[2*i+1]);

    float p2[32];
    #pragma unroll
    for (int j = 0; j < 32; ++j) p2[j] = 0.0f;
    for (int k = 0; k < 32; ++k) {
        const float a = x[k];
        const float* w = We1 + (32 + k) * 32;
        #pragma unroll
        for (int j = 0; j < 32; ++j) p2[j] = fmaf(a, w[j], p2[j]);
    }
    unsigned* ps = Ps + (size_t)n * 16;
    #pragma unroll
    for (int i = 0; i < 16; ++i) ps[i] = pack_bf2(p2[2*i], p2[2*i+1]);
}

// ---------- pass 2: per-edge MLPs (h2@Wn2 via MFMA) + coalesced atomics ----------
__global__ void __launch_bounds__(256) mpn_main(
    const unsigned* __restrict__ Pd,
    const unsigned* __restrict__ Ps,
    const float* __restrict__ x_edge,
    const int* __restrict__ src,
    const int* __restrict__ dst,
    const float* __restrict__ We1,  // rows 64..69
    const float* __restrict__ We2, const float* __restrict__ be2,
    const float* __restrict__ Wn1,  // rows 32..37
    const short* __restrict__ Wn2T, // [32][64] bf16
    const float* __restrict__ bn2,
    float* __restrict__ nm_out,   // [N_NODES, 32]
    float* __restrict__ em_out)   // [N_EDGES, 6]
{
    // Per-wave h2 tiles: 4 waves x 64 rows x 72 bf16 (stride 144 B: 16B-aligned
    // b128 ops, bank-balanced). Reused afterwards as s_nm[128][33] f32 staging.
    __shared__ unsigned s_h2[4][64][36];   // 36864 B
    __shared__ int      s_dst[128];

    const int tid  = threadIdx.x;
    const int lane = tid & 63;
    const int wave = tid >> 6;
    const int quad = lane >> 4;
    const int l15  = lane & 15;

    const int e = blockIdx.x * 256 + tid;
    const int d = dst[e];
    const int s = src[e];

    const uint4* pdrow = (const uint4*)(Pd + (size_t)d * 48);
    const uint4* psrow = (const uint4*)(Ps + (size_t)s * 16);

    // ---- edge MLP layer 1: h1 = relu(P1[d] + P2[s] + xe @ We1[64:70])
    float h1[32];
    #pragma unroll
    for (int i = 0; i < 4; ++i) {
        uint4 va = pdrow[i];
        uint4 vb = psrow[i];
        h1[8*i+0] = bflo(va.x) + bflo(vb.x);
        h1[8*i+1] = bfhi(va.x) + bfhi(vb.x);
        h1[8*i+2] = bflo(va.y) + bflo(vb.y);
        h1[8*i+3] = bfhi(va.y) + bfhi(vb.y);
        h1[8*i+4] = bflo(va.z) + bflo(vb.z);
        h1[8*i+5] = bfhi(va.z) + bfhi(vb.z);
        h1[8*i+6] = bflo(va.w) + bflo(vb.w);
        h1[8*i+7] = bfhi(va.w) + bfhi(vb.w);
    }

    // hoist the P3 half of the Pd row: all 12 scattered Pd/Ps line-loads are now
    // in flight together; their latency hides under the We1-tail + em loops.
    // (session-proven in R3; pure scheduling change)
    const uint4 q0 = pdrow[4],  q1 = pdrow[5],  q2 = pdrow[6],  q3 = pdrow[7];
    const uint4 q4 = pdrow[8],  q5 = pdrow[9],  q6 = pdrow[10], q7 = pdrow[11];

    float xe[6];
    {
        const float2* pe = (const float2*)(x_edge + (size_t)e * 6);
        float2 a = pe[0], b = pe[1], c = pe[2];
        xe[0]=a.x; xe[1]=a.y; xe[2]=b.x; xe[3]=b.y; xe[4]=c.x; xe[5]=c.y;
    }
    #pragma unroll
    for (int k = 0; k < 6; ++k) {
        const float a = xe[k];
        const float* w = We1 + (64 + k) * 32;
        #pragma unroll
        for (int j = 0; j < 32; ++j) h1[j] = fmaf(a, w[j], h1[j]);
    }
    #pragma unroll
    for (int j = 0; j < 32; ++j) h1[j] = fmaxf(h1[j], 0.0f);

    // ---- edge MLP layer 2: em = relu(h1 @ We2 + be2)
    float em[6];
    #pragma unroll
    for (int j = 0; j < 6; ++j) em[j] = be2[j];
    for (int k = 0; k < 32; ++k) {
        const float a = h1[k];
        const float* w = We2 + k * 6;
        #pragma unroll
        for (int j = 0; j < 6; ++j) em[j] = fmaf(a, w[j], em[j]);
    }
    #pragma unroll
    for (int j = 0; j < 6; ++j) em[j] = fmaxf(em[j], 0.0f);

    {
        float2* eo = (float2*)(em_out + (size_t)e * 6);
        eo[0] = make_float2(em[0], em[1]);
        eo[1] = make_float2(em[2], em[3]);
        eo[2] = make_float2(em[4], em[5]);
    }

    // ---- node MLP layer 1: h2 = relu(P3[d] + em @ Wn1[32:38])
    float h2[64];
    {
        uint4 qq[8] = {q0, q1, q2, q3, q4, q5, q6, q7};
        #pragma unroll
        for (int i = 0; i < 8; ++i) {
            uint4 v = qq[i];
            h2[8*i+0] = bflo(v.x); h2[8*i+1] = bfhi(v.x);
            h2[8*i+2] = bflo(v.y); h2[8*i+3] = bfhi(v.y);
            h2[8*i+4] = bflo(v.z); h2[8*i+5] = bfhi(v.z);
            h2[8*i+6] = bflo(v.w); h2[8*i+7] = bfhi(v.w);
        }
    }
    #pragma unroll
    for (int k = 0; k < 6; ++k) {
        const float a = em[k];
        const float* w = Wn1 + (32 + k) * 64;
        #pragma unroll
        for (int j = 0; j < 64; ++j) h2[j] = fmaf(a, w[j], h2[j]);
    }

    // pack relu(h2) -> bf16, stage in this wave's LDS tile (row = lane)
    {
        uint4* row = (uint4*)&s_h2[wave][lane][0];
        #pragma unroll
        for (int i = 0; i < 8; ++i) {
            uint4 v;
            v.x = pack_bf2(fmaxf(h2[8*i+0],0.f), fmaxf(h2[8*i+1],0.f));
            v.y = pack_bf2(fmaxf(h2[8*i+2],0.f), fmaxf(h2[8*i+3],0.f));
            v.z = pack_bf2(fmaxf(h2[8*i+4],0.f), fmaxf(h2[8*i+5],0.f));
            v.w = pack_bf2(fmaxf(h2[8*i+6],0.f), fmaxf(h2[8*i+7],0.f));
            row[i] = v;
        }
    }
    // NO barrier here: each wave reads only its own tile below (wave-synchronous
    // LDS; session-proven in R3/R4). The chunk-loop barriers still protect the
    // s_h2 -> s_nm overlay against cross-wave reuse.

    // ---- nm = h2 @ Wn2 via MFMA: M=64 edges, N=32 outs, K=64
    // B frags from Wn2T[n][k] (global, L1-resident): lane holds B[n=l15][k=quad*8+j]
    bf16x8 bfr[2][2];
    #pragma unroll
    for (int n = 0; n < 2; ++n)
        #pragma unroll
        for (int kt = 0; kt < 2; ++kt)
            bfr[n][kt] = *(const bf16x8*)(Wn2T + (n*16 + l15)*64 + kt*32 + quad*8);

    f32x4 acc[4][2];
    #pragma unroll
    for (int m = 0; m < 4; ++m) { acc[m][0] = (f32x4)0.f; acc[m][1] = (f32x4)0.f; }

    #pragma unroll
    for (int m = 0; m < 4; ++m) {
        #pragma unroll
        for (int kt = 0; kt < 2; ++kt) {
            // A[m'=l15][k=quad*8+j] from edge row m*16+l15 of this wave's tile
            bf16x8 af = *(const bf16x8*)((const char*)&s_h2[wave][m*16 + l15][0]
                                         + kt*64 + quad*16);
            acc[m][0] = __builtin_amdgcn_mfma_f32_16x16x32_bf16(af, bfr[0][kt], acc[m][0], 0, 0, 0);
            acc[m][1] = __builtin_amdgcn_mfma_f32_16x16x32_bf16(af, bfr[1][kt], acc[m][1], 0, 0, 0);
        }
    }

    const float b0 = bn2[l15];
    const float b1 = bn2[16 + l15];

    // ---- coalesced atomic segment-sum, 2 chunks of 128 edges
    // (LDS tile reused as s_nm[128][33] f32)
    float* s_nm = (float*)s_h2;
    #pragma unroll
    for (int chunk = 0; chunk < 2; ++chunk) {
        __syncthreads();
        if ((tid >> 7) == chunk) {
            s_dst[tid & 127] = d;                        // own edge's dst
            const int be = (wave & 1) * 64;              // C-layout scatter
            #pragma unroll
            for (int m = 0; m < 4; ++m) {
                #pragma unroll
                for (int n = 0; n < 2; ++n) {
                    const float bb = n ? b1 : b0;
                    #pragma unroll
                    for (int r = 0; r < 4; ++r) {
                        const int le  = be + m*16 + quad*4 + r;   // edge (row)
                        const int out = n*16 + l15;               // feature (col)
                        s_nm[le*33 + out] = fmaxf(acc[m][n][r] + bb, 0.0f);
                    }
                }
            }
        }
        __syncthreads();
        #pragma unroll 4
        for (int it = 0; it < 16; ++it) {
            const int f  = it * 256 + tid;   // 128 edges x 32 feats
            const int le = f >> 5;
            const int j  = f & 31;
            atomicAdd(nm_out + (size_t)s_dst[le] * 32 + j, s_nm[le*33 + j]);
        }
    }
}

extern "C" void kernel_launch(void* const* d_in, const int* in_sizes, int n_in,
                              void* d_out, int out_size, void* d_ws, size_t ws_size,
                              hipStream_t stream) {
    const float* x_node = (const float*)d_in[0];
    const float* x_edge = (const float*)d_in[1];
    const int*   src    = (const int*)d_in[2];
    const int*   dst    = (const int*)d_in[3];
    const float* We1 = (const float*)d_in[4];
    const float* be1 = (const float*)d_in[5];
    const float* We2 = (const float*)d_in[6];
    const float* be2 = (const float*)d_in[7];
    const float* Wn1 = (const float*)d_in[8];
    const float* bn1 = (const float*)d_in[9];
    const float* Wn2 = (const float*)d_in[10];
    const float* bn2 = (const float*)d_in[11];

    float* nm_out = (float*)d_out;                        // [N_NODES*32]
    float* em_out = (float*)d_out + (size_t)N_NODES * 32; // [N_EDGES*6]

    // workspace: bf16 per-node projection tables (25.6 MB) + Wn2^T (4 KB)
    unsigned* Pd   = (unsigned*)d_ws;               // [N_NODES][48] packed bf16x2
    unsigned* Ps   = Pd + (size_t)N_NODES * 48;     // [N_NODES][16]
    short*    Wn2T = (short*)(Ps + (size_t)N_NODES * 16);  // [32][64] bf16

    mpn_precompute<<<(N_NODES + 255) / 256, 256, 0, stream>>>(
        x_node, We1, be1, Wn1, bn1, Wn2, Pd, Ps, Wn2T, nm_out);

    mpn_main<<<N_EDGES / 256, 256, 0, stream>>>(
        Pd, Ps, x_edge, src, dst,
        We1, We2, be2, Wn1, Wn2T, bn2,
        nm_out, em_out);
}